// Round 4
// baseline (484.528 us; speedup 1.0000x reference)
//
#include <hip/hip_runtime.h>

#define N1 16384
#define N2 4096
#define CC 128
#define KIN 384
#define HID 256

typedef unsigned short u16;
typedef unsigned int u32;

typedef _Float16 v8h __attribute__((ext_vector_type(8)));
typedef float v4f __attribute__((ext_vector_type(4)));

// ---------- workspace layout (bytes) ----------
// W0h  fp16 256x384           @ 0        (196608)
// W1h  fp16 256x256           @ 196608   (131072)
// sst  fp32 s0,t0,s1,t1 x256  @ 327680   (4096)
// xyz2q float4 B*N2           @ 331776   (262144)
// idx3 int B*N1*3             @ 593920   (786432)
// w3   fp32 B*N1*3            @ 1380352  (786432)
// p2t  fp32 B*N2*C            @ 2166784  (8388608)
// total = 10555392

__device__ __forceinline__ u16 f2h(float f) {
    _Float16 h = (_Float16)f;
    return __builtin_bit_cast(u16, h);
}

// =====================================================================
// Prep: convert weights to fp16, fold BN into scale/shift, build xyz2q
// =====================================================================
__global__ __launch_bounds__(256) void prep_kernel(
    const float* __restrict__ w0, const float* __restrict__ w1,
    const float* __restrict__ b0, const float* __restrict__ g0, const float* __restrict__ be0,
    const float* __restrict__ m0, const float* __restrict__ v0,
    const float* __restrict__ b1, const float* __restrict__ g1, const float* __restrict__ be1,
    const float* __restrict__ m1, const float* __restrict__ v1,
    const float* __restrict__ xyz2,
    u16* __restrict__ W0h, u16* __restrict__ W1h,
    float* __restrict__ sst, float4* __restrict__ xyz2q)
{
    int id = blockIdx.x * 256 + threadIdx.x;
    if (id < 98304) {
        W0h[id] = f2h(w0[id]);
    } else if (id < 163840) {
        int t = id - 98304;
        W1h[t] = f2h(w1[t]);
    } else if (id < 164352) {
        int t = id - 163840;
        int o = t & 255;
        if (t < 256) {
            float s = g0[o] * rsqrtf(v0[o] + 1e-5f);
            sst[o]       = s;
            sst[256 + o] = (b0[o] - m0[o]) * s + be0[o];
        } else {
            float s = g1[o] * rsqrtf(v1[o] + 1e-5f);
            sst[512 + o] = s;
            sst[768 + o] = (b1[o] - m1[o]) * s + be1[o];
        }
    } else if (id < 180736) {
        int t = id - 164352;  // b*N2+n
        float x = xyz2[(size_t)t * 3 + 0];
        float y = xyz2[(size_t)t * 3 + 1];
        float z = xyz2[(size_t)t * 3 + 2];
        xyz2q[t] = make_float4(x, y, z, fmaf(x, x, fmaf(y, y, z * z)));
    }
}

// =====================================================================
// Transpose points2 (B,C,N2) -> p2t (B,N2,C), LDS-tiled
// =====================================================================
__global__ __launch_bounds__(256) void transpose_kernel(
    const float* __restrict__ points2, float* __restrict__ p2t)
{
    __shared__ float tile[32][65];
    int n20 = blockIdx.x * 64;
    int c0  = blockIdx.y * 32;
    int b   = blockIdx.z;
    int tid = threadIdx.x;
    int n2i = tid & 63, ci = tid >> 6;
    for (int cc = ci; cc < 32; cc += 4)
        tile[cc][n2i] = points2[((size_t)b * CC + (c0 + cc)) * N2 + n20 + n2i];
    __syncthreads();
    int co = tid & 31, ro = tid >> 5;
    for (int rr = ro; rr < 64; rr += 8)
        p2t[((size_t)b * N2 + n20 + rr) * CC + c0 + co] = tile[co][rr];
}

// =====================================================================
// 3-NN + inverse-distance weights
// 256 thr / block, 64 queries / block, 8 queries / thread,
// 32-way candidate split per query group; candidates staged in
// 2 stages x 2048 float4 (32 KB LDS) -> 4 blocks/CU (grid-exact fill).
// Inner loop branchless: med3/min distance network + cndmask indices.
// =====================================================================
__device__ __forceinline__ void ins3lex(float t, int j,
    float& d0, float& d1, float& d2, int& i0, int& i1, int& i2)
{
    if (t < d2 || (t == d2 && j < i2)) {
        if (t < d1 || (t == d1 && j < i1)) {
            d2 = d1; i2 = i1;
            if (t < d0 || (t == d0 && j < i0)) { d1 = d0; i1 = i0; d0 = t; i0 = j; }
            else                               { d1 = t;  i1 = j; }
        } else { d2 = t; i2 = j; }
    }
}

__global__ __launch_bounds__(256, 4) void knn_kernel(
    const float* __restrict__ xyz1, const float4* __restrict__ xyz2q,
    int* __restrict__ idx3, float* __restrict__ w3)
{
    __shared__ float4 slds[2048];   // 32768 B

    int tid = threadIdx.x;
    int b   = blockIdx.y;
    int n0  = blockIdx.x * 64;

    int s  = tid & 31;      // candidate split (lane bits 0..4)
    int g  = tid >> 5;      // query group 0..7
    int p0 = n0 + g * 8;

    float ax[8], ay[8], az[8], pp[8];
#pragma unroll
    for (int q = 0; q < 8; ++q) {
        size_t pb = ((size_t)b * N1 + p0 + q) * 3;
        float x = xyz1[pb], y = xyz1[pb + 1], z = xyz1[pb + 2];
        ax[q] = -2.f * x; ay[q] = -2.f * y; az[q] = -2.f * z;
        pp[q] = fmaf(x, x, fmaf(y, y, z * z));
    }

    float d0[8], d1[8], d2[8];
    int   i0[8], i1[8], i2[8];
#pragma unroll
    for (int q = 0; q < 8; ++q) {
        d0[q] = 1e30f; d1[q] = 1e30f; d2[q] = 1e30f;
        i0[q] = 0;     i1[q] = 0;     i2[q] = 0;
    }

    for (int stage = 0; stage < 2; ++stage) {
        int base = stage * 2048;
        // stage candidates to LDS (coalesced 16B)
        for (int i = tid; i < 2048; i += 256)
            slds[i] = xyz2q[(size_t)b * N2 + base + i];
        __syncthreads();

        // thread s scans candidates s, s+32, ... (ascending across stages ->
        // strict < keeps lowest-index-on-tie, matching stable top_k).
#pragma unroll 2
        for (int k = 0; k < 2048 / 32; ++k) {
            int c = s + (k << 5);
            float4 v = slds[c];
            int cand = base + c;
#pragma unroll
            for (int q = 0; q < 8; ++q) {
                float t = fmaf(ax[q], v.x, fmaf(ay[q], v.y, fmaf(az[q], v.z, v.w)));
                // branchless top-3 insert (v_cmp/v_cndmask/v_med3)
                bool c0 = t < d0[q];
                bool c1 = t < d1[q];
                bool c2 = t < d2[q];
                i2[q] = c1 ? i1[q] : (c2 ? cand : i2[q]);   // uses old i1
                i1[q] = c0 ? i0[q] : (c1 ? cand : i1[q]);   // uses old i0
                i0[q] = c0 ? cand : i0[q];
                d2[q] = __builtin_amdgcn_fmed3f(d1[q], t, d2[q]);  // old d1
                d1[q] = __builtin_amdgcn_fmed3f(d0[q], t, d1[q]);  // old d0
                d0[q] = fminf(t, d0[q]);
            }
        }
        __syncthreads();   // protect LDS overwrite by next stage
    }

    // butterfly merge across the 32 splits (lex tie-break by true index)
#pragma unroll
    for (int st = 1; st <= 16; st <<= 1) {
#pragma unroll
        for (int q = 0; q < 8; ++q) {
            float e0 = __shfl_xor(d0[q], st, 64);
            float e1 = __shfl_xor(d1[q], st, 64);
            float e2 = __shfl_xor(d2[q], st, 64);
            int   j0 = __shfl_xor(i0[q], st, 64);
            int   j1 = __shfl_xor(i1[q], st, 64);
            int   j2 = __shfl_xor(i2[q], st, 64);
            ins3lex(e0, j0, d0[q], d1[q], d2[q], i0[q], i1[q], i2[q]);
            ins3lex(e1, j1, d0[q], d1[q], d2[q], i0[q], i1[q], i2[q]);
            ins3lex(e2, j2, d0[q], d1[q], d2[q], i0[q], i1[q], i2[q]);
        }
    }

    if (s == 0) {
#pragma unroll
        for (int q = 0; q < 8; ++q) {
            float r0 = 1.f / (d0[q] + pp[q]);
            float r1 = 1.f / (d1[q] + pp[q]);
            float r2 = 1.f / (d2[q] + pp[q]);
            float inv = 1.f / (r0 + r1 + r2);
            size_t o3 = ((size_t)b * N1 + p0 + q) * 3;
            idx3[o3]     = i0[q];
            idx3[o3 + 1] = i1[q];
            idx3[o3 + 2] = i2[q];
            w3[o3]     = r0 * inv;
            w3[o3 + 1] = r1 * inv;
            w3[o3 + 2] = r2 * inv;
        }
    }
}

// =====================================================================
// Fused interpolate + concat + MLP(384->256->256, BN+ReLU) + channel max
// block = 256 thr (4 waves, 2x2 over o/p), 64 points per block
// =====================================================================
__global__ __launch_bounds__(256, 3) void mlp_kernel(
    const float* __restrict__ points1, const float* __restrict__ pointsb1,
    const float4* __restrict__ p2t4,
    const int* __restrict__ idx3, const float* __restrict__ w3,
    const uint4* __restrict__ W0v, const uint4* __restrict__ W1v,
    const float* __restrict__ sst, float* __restrict__ out)
{
    // x: 64 rows x 384 fp16, 16B-chunk swizzled by (p&7); h1 overlays (64x256)
    __shared__ __align__(16) u16 sx[64 * KIN];   // 49152 B
    __shared__ float sred[2][64];
    __shared__ int   s_idx[192];
    __shared__ float s_w[192];

    int tid = threadIdx.x;
    int b   = blockIdx.y;
    int n0  = blockIdx.x * 64;

    if (tid < 192) {
        size_t gi = ((size_t)b * N1 + n0) * 3 + tid;
        s_idx[tid] = idx3[gi];
        s_w[tid]   = w3[gi];
    }
    __syncthreads();

    // ---- stage x rows 0..127 (points1) ----
    for (int i = tid; i < 2048; i += 256) {
        int p = i & 63, r4 = (i >> 6) * 4;
        size_t base = ((size_t)b * CC + r4) * N1 + n0 + p;
        float a0 = points1[base];
        float a1 = points1[base + (size_t)N1];
        float a2 = points1[base + (size_t)2 * N1];
        float a3 = points1[base + (size_t)3 * N1];
        u32 lo = f2h(a0) | ((u32)f2h(a1) << 16);
        u32 hi = f2h(a2) | ((u32)f2h(a3) << 16);
        int chunk = (r4 >> 3) ^ (p & 7);
        *(uint2*)&sx[p * KIN + chunk * 8 + (r4 & 7)] = make_uint2(lo, hi);
    }
    // ---- stage x rows 256..383 (points_b1) ----
    for (int i = tid; i < 2048; i += 256) {
        int p = i & 63, r4 = (i >> 6) * 4;
        size_t base = ((size_t)b * CC + r4) * N1 + n0 + p;
        float a0 = pointsb1[base];
        float a1 = pointsb1[base + (size_t)N1];
        float a2 = pointsb1[base + (size_t)2 * N1];
        float a3 = pointsb1[base + (size_t)3 * N1];
        int k4 = 256 + r4;
        u32 lo = f2h(a0) | ((u32)f2h(a1) << 16);
        u32 hi = f2h(a2) | ((u32)f2h(a3) << 16);
        int chunk = (k4 >> 3) ^ (p & 7);
        *(uint2*)&sx[p * KIN + chunk * 8 + (k4 & 7)] = make_uint2(lo, hi);
    }
    // ---- stage x rows 128..255: 3-NN interpolation from p2t rows ----
    for (int i = tid; i < 2048; i += 256) {
        int c4 = i & 31, p = i >> 5;
        float w0w = s_w[p * 3 + 0], w1w = s_w[p * 3 + 1], w2w = s_w[p * 3 + 2];
        float4 f0 = p2t4[((size_t)b * N2 + s_idx[p * 3 + 0]) * 32 + c4];
        float4 f1 = p2t4[((size_t)b * N2 + s_idx[p * 3 + 1]) * 32 + c4];
        float4 f2 = p2t4[((size_t)b * N2 + s_idx[p * 3 + 2]) * 32 + c4];
        float e0 = fmaf(w0w, f0.x, fmaf(w1w, f1.x, w2w * f2.x));
        float e1 = fmaf(w0w, f0.y, fmaf(w1w, f1.y, w2w * f2.y));
        float e2 = fmaf(w0w, f0.z, fmaf(w1w, f1.z, w2w * f2.z));
        float e3 = fmaf(w0w, f0.w, fmaf(w1w, f1.w, w2w * f2.w));
        int k4 = 128 + c4 * 4;
        u32 lo = f2h(e0) | ((u32)f2h(e1) << 16);
        u32 hi = f2h(e2) | ((u32)f2h(e3) << 16);
        int chunk = (k4 >> 3) ^ (p & 7);
        *(uint2*)&sx[p * KIN + chunk * 8 + (k4 & 7)] = make_uint2(lo, hi);
    }
    __syncthreads();

    int lane = tid & 63, wave = tid >> 6;
    int wo = wave >> 1, wp = wave & 1;      // o-half, p-half
    int ml = lane & 15, ql = lane >> 4;     // frag row/col, quad
    int p0  = wp * 32 + ml;                 // p for pt=0 (pt=1: +16)
    int px7 = ml & 7;                       // == p&7 for both pt

    // ---------------- GEMM1: h1 = W0 @ x ----------------
    v4f acc1[8][2];
#pragma unroll
    for (int ot = 0; ot < 8; ++ot)
        for (int pt = 0; pt < 2; ++pt)
            acc1[ot][pt] = (v4f){0.f, 0.f, 0.f, 0.f};

#pragma unroll
    for (int s = 0; s < 12; ++s) {
        int kc = s * 4 + ql;
        int pc = (kc ^ px7) * 8;
        v8h bf0 = __builtin_bit_cast(v8h, *(const uint4*)&sx[p0 * KIN + pc]);
        v8h bf1 = __builtin_bit_cast(v8h, *(const uint4*)&sx[(p0 + 16) * KIN + pc]);
#pragma unroll
        for (int ot = 0; ot < 8; ++ot) {
            int o = wo * 128 + ot * 16 + ml;
            v8h af = __builtin_bit_cast(v8h, W0v[o * 48 + kc]);
            acc1[ot][0] = __builtin_amdgcn_mfma_f32_16x16x32_f16(af, bf0, acc1[ot][0], 0, 0, 0);
            acc1[ot][1] = __builtin_amdgcn_mfma_f32_16x16x32_f16(af, bf1, acc1[ot][1], 0, 0, 0);
        }
    }
    __syncthreads();   // all x reads done before h1 overlays sx

    // epilogue 1: BN+ReLU -> fp16 h1[p][o] (row stride 256, swizzled)
    const float* s0v = sst;
    const float* t0v = sst + 256;
#pragma unroll
    for (int ot = 0; ot < 8; ++ot) {
        int o0 = wo * 128 + ot * 16 + ql * 4;
        float sc0 = s0v[o0], sc1 = s0v[o0 + 1], sc2 = s0v[o0 + 2], sc3 = s0v[o0 + 3];
        float sh0 = t0v[o0], sh1 = t0v[o0 + 1], sh2 = t0v[o0 + 2], sh3 = t0v[o0 + 3];
        int chunk = ((o0 >> 3) ^ px7);
#pragma unroll
        for (int pt = 0; pt < 2; ++pt) {
            int p = p0 + pt * 16;
            float z0 = fmaxf(fmaf(acc1[ot][pt][0], sc0, sh0), 0.f);
            float z1 = fmaxf(fmaf(acc1[ot][pt][1], sc1, sh1), 0.f);
            float z2 = fmaxf(fmaf(acc1[ot][pt][2], sc2, sh2), 0.f);
            float z3 = fmaxf(fmaf(acc1[ot][pt][3], sc3, sh3), 0.f);
            u32 lo = f2h(z0) | ((u32)f2h(z1) << 16);
            u32 hi = f2h(z2) | ((u32)f2h(z3) << 16);
            *(uint2*)&sx[p * HID + chunk * 8 + (o0 & 7)] = make_uint2(lo, hi);
        }
    }
    __syncthreads();

    // ---------------- GEMM2: h2 = W1 @ h1 ----------------
    v4f acc2[8][2];
#pragma unroll
    for (int ot = 0; ot < 8; ++ot)
        for (int pt = 0; pt < 2; ++pt)
            acc2[ot][pt] = (v4f){0.f, 0.f, 0.f, 0.f};

#pragma unroll
    for (int s = 0; s < 8; ++s) {
        int kc = s * 4 + ql;
        int pc = (kc ^ px7) * 8;
        v8h bf0 = __builtin_bit_cast(v8h, *(const uint4*)&sx[p0 * HID + pc]);
        v8h bf1 = __builtin_bit_cast(v8h, *(const uint4*)&sx[(p0 + 16) * HID + pc]);
#pragma unroll
        for (int ot = 0; ot < 8; ++ot) {
            int o = wo * 128 + ot * 16 + ml;
            v8h af = __builtin_bit_cast(v8h, W1v[o * 32 + kc]);
            acc2[ot][0] = __builtin_amdgcn_mfma_f32_16x16x32_f16(af, bf0, acc2[ot][0], 0, 0, 0);
            acc2[ot][1] = __builtin_amdgcn_mfma_f32_16x16x32_f16(af, bf1, acc2[ot][1], 0, 0, 0);
        }
    }

    // epilogue 2: BN + ReLU (via max with 0) + channel max
    const float* s1v = sst + 512;
    const float* t1v = sst + 768;
    float mx0 = 0.f, mx1 = 0.f;   // relu floor = 0
#pragma unroll
    for (int ot = 0; ot < 8; ++ot) {
        int o0 = wo * 128 + ot * 16 + ql * 4;
#pragma unroll
        for (int r = 0; r < 4; ++r) {
            float sc = s1v[o0 + r], sh = t1v[o0 + r];
            mx0 = fmaxf(mx0, fmaf(acc2[ot][0][r], sc, sh));
            mx1 = fmaxf(mx1, fmaf(acc2[ot][1][r], sc, sh));
        }
    }
    mx0 = fmaxf(mx0, __shfl_xor(mx0, 16, 64));
    mx0 = fmaxf(mx0, __shfl_xor(mx0, 32, 64));
    mx1 = fmaxf(mx1, __shfl_xor(mx1, 16, 64));
    mx1 = fmaxf(mx1, __shfl_xor(mx1, 32, 64));
    if (lane < 16) {
        sred[wo][wp * 32 + lane]      = mx0;
        sred[wo][wp * 32 + 16 + lane] = mx1;
    }
    __syncthreads();
    if (tid < 64)
        out[(size_t)b * N1 + n0 + tid] = fmaxf(sred[0][tid], sred[1][tid]);
}

// =====================================================================
extern "C" void kernel_launch(void* const* d_in, const int* in_sizes, int n_in,
                              void* d_out, int out_size, void* d_ws, size_t ws_size,
                              hipStream_t stream)
{
    const float* xyz1     = (const float*)d_in[0];
    const float* xyz2     = (const float*)d_in[1];
    const float* points2  = (const float*)d_in[2];
    const float* points1  = (const float*)d_in[3];
    const float* pointsb1 = (const float*)d_in[4];
    const float* w0   = (const float*)d_in[5];
    const float* b0   = (const float*)d_in[6];
    const float* g0   = (const float*)d_in[7];
    const float* be0  = (const float*)d_in[8];
    const float* m0   = (const float*)d_in[9];
    const float* v0   = (const float*)d_in[10];
    const float* w1   = (const float*)d_in[11];
    const float* b1   = (const float*)d_in[12];
    const float* g1   = (const float*)d_in[13];
    const float* be1  = (const float*)d_in[14];
    const float* m1   = (const float*)d_in[15];
    const float* v1   = (const float*)d_in[16];
    float* out = (float*)d_out;

    char* ws = (char*)d_ws;
    u16*    W0h   = (u16*)(ws + 0);
    u16*    W1h   = (u16*)(ws + 196608);
    float*  sst   = (float*)(ws + 327680);
    float4* xyz2q = (float4*)(ws + 331776);
    int*    idx3  = (int*)(ws + 593920);
    float*  w3    = (float*)(ws + 1380352);
    float*  p2t   = (float*)(ws + 2166784);

    prep_kernel<<<706, 256, 0, stream>>>(w0, w1, b0, g0, be0, m0, v0,
                                         b1, g1, be1, m1, v1, xyz2,
                                         W0h, W1h, sst, xyz2q);
    transpose_kernel<<<dim3(64, 4, 4), 256, 0, stream>>>(points2, p2t);
    knn_kernel<<<dim3(256, 4), 256, 0, stream>>>(xyz1, xyz2q, idx3, w3);
    mlp_kernel<<<dim3(256, 4), 256, 0, stream>>>(points1, pointsb1,
                                                 (const float4*)p2t, idx3, w3,
                                                 (const uint4*)W0h, (const uint4*)W1h,
                                                 sst, out);
}

// Round 5
// 400.907 us; speedup vs baseline: 1.2086x; 1.2086x over previous
//
#include <hip/hip_runtime.h>

#define N1 16384
#define N2 4096
#define CC 128
#define KIN 384
#define HID 256

typedef unsigned short u16;
typedef unsigned int u32;

typedef _Float16 v8h __attribute__((ext_vector_type(8)));
typedef float v4f __attribute__((ext_vector_type(4)));

// ---------- workspace layout (bytes) ----------
// W0h  fp16 256x384           @ 0        (196608)
// W1h  fp16 256x256           @ 196608   (131072)
// sst  fp32 s0,t0,s1,t1 x256  @ 327680   (4096)
// xyz2q float4 B*N2           @ 331776   (262144)
// idx3 int B*N1*3             @ 593920   (786432)
// w3   fp32 B*N1*3            @ 1380352  (786432)
// p2t  fp32 B*N2*C            @ 2166784  (8388608)
// total = 10555392

__device__ __forceinline__ u16 f2h(float f) {
    _Float16 h = (_Float16)f;
    return __builtin_bit_cast(u16, h);
}

// =====================================================================
// Prep: convert weights to fp16, fold BN into scale/shift, build xyz2q
// =====================================================================
__global__ __launch_bounds__(256) void prep_kernel(
    const float* __restrict__ w0, const float* __restrict__ w1,
    const float* __restrict__ b0, const float* __restrict__ g0, const float* __restrict__ be0,
    const float* __restrict__ m0, const float* __restrict__ v0,
    const float* __restrict__ b1, const float* __restrict__ g1, const float* __restrict__ be1,
    const float* __restrict__ m1, const float* __restrict__ v1,
    const float* __restrict__ xyz2,
    u16* __restrict__ W0h, u16* __restrict__ W1h,
    float* __restrict__ sst, float4* __restrict__ xyz2q)
{
    int id = blockIdx.x * 256 + threadIdx.x;
    if (id < 98304) {
        W0h[id] = f2h(w0[id]);
    } else if (id < 163840) {
        int t = id - 98304;
        W1h[t] = f2h(w1[t]);
    } else if (id < 164352) {
        int t = id - 163840;
        int o = t & 255;
        if (t < 256) {
            float s = g0[o] * rsqrtf(v0[o] + 1e-5f);
            sst[o]       = s;
            sst[256 + o] = (b0[o] - m0[o]) * s + be0[o];
        } else {
            float s = g1[o] * rsqrtf(v1[o] + 1e-5f);
            sst[512 + o] = s;
            sst[768 + o] = (b1[o] - m1[o]) * s + be1[o];
        }
    } else if (id < 180736) {
        int t = id - 164352;  // b*N2+n
        float x = xyz2[(size_t)t * 3 + 0];
        float y = xyz2[(size_t)t * 3 + 1];
        float z = xyz2[(size_t)t * 3 + 2];
        xyz2q[t] = make_float4(x, y, z, fmaf(x, x, fmaf(y, y, z * z)));
    }
}

// =====================================================================
// Transpose points2 (B,C,N2) -> p2t (B,N2,C), LDS-tiled
// =====================================================================
__global__ __launch_bounds__(256) void transpose_kernel(
    const float* __restrict__ points2, float* __restrict__ p2t)
{
    __shared__ float tile[32][65];
    int n20 = blockIdx.x * 64;
    int c0  = blockIdx.y * 32;
    int b   = blockIdx.z;
    int tid = threadIdx.x;
    int n2i = tid & 63, ci = tid >> 6;
    for (int cc = ci; cc < 32; cc += 4)
        tile[cc][n2i] = points2[((size_t)b * CC + (c0 + cc)) * N2 + n20 + n2i];
    __syncthreads();
    int co = tid & 31, ro = tid >> 5;
    for (int rr = ro; rr < 64; rr += 8)
        p2t[((size_t)b * N2 + n20 + rr) * CC + c0 + co] = tile[co][rr];
}

// =====================================================================
// 3-NN + inverse-distance weights
// 256 thr / block, 64 queries / block, 4 queries / thread,
// 16-way candidate split; candidates staged in 2 stages x 2048 float4
// (32 KB LDS). Grid 1024 = 4 blocks/CU; natural VGPRs (~88) -> no spill.
// Inner loop branchless: med3/min distance network + cndmask indices.
// =====================================================================
__device__ __forceinline__ void ins3lex(float t, int j,
    float& d0, float& d1, float& d2, int& i0, int& i1, int& i2)
{
    if (t < d2 || (t == d2 && j < i2)) {
        if (t < d1 || (t == d1 && j < i1)) {
            d2 = d1; i2 = i1;
            if (t < d0 || (t == d0 && j < i0)) { d1 = d0; i1 = i0; d0 = t; i0 = j; }
            else                               { d1 = t;  i1 = j; }
        } else { d2 = t; i2 = j; }
    }
}

__global__ __launch_bounds__(256) void knn_kernel(
    const float* __restrict__ xyz1, const float4* __restrict__ xyz2q,
    int* __restrict__ idx3, float* __restrict__ w3)
{
    __shared__ float4 slds[2048];   // 32768 B

    int tid = threadIdx.x;
    int b   = blockIdx.y;
    int n0  = blockIdx.x * 64;

    int s  = tid & 15;      // candidate split (lane bits 0..3)
    int g  = tid >> 4;      // query group 0..15
    int p0 = n0 + g * 4;

    float ax[4], ay[4], az[4], pp[4];
#pragma unroll
    for (int q = 0; q < 4; ++q) {
        size_t pb = ((size_t)b * N1 + p0 + q) * 3;
        float x = xyz1[pb], y = xyz1[pb + 1], z = xyz1[pb + 2];
        ax[q] = -2.f * x; ay[q] = -2.f * y; az[q] = -2.f * z;
        pp[q] = fmaf(x, x, fmaf(y, y, z * z));
    }

    float d0[4], d1[4], d2[4];
    int   i0[4], i1[4], i2[4];
#pragma unroll
    for (int q = 0; q < 4; ++q) {
        d0[q] = 1e30f; d1[q] = 1e30f; d2[q] = 1e30f;
        i0[q] = 0;     i1[q] = 0;     i2[q] = 0;
    }

    for (int stage = 0; stage < 2; ++stage) {
        int base = stage * 2048;
        // stage candidates to LDS (coalesced 16B)
        for (int i = tid; i < 2048; i += 256)
            slds[i] = xyz2q[(size_t)b * N2 + base + i];
        __syncthreads();

        // thread s scans candidates s, s+16, ... (ascending across stages ->
        // strict < keeps lowest-index-on-tie, matching stable top_k).
#pragma unroll 4
        for (int k = 0; k < 2048 / 16; ++k) {
            int c = s + (k << 4);
            float4 v = slds[c];
            int cand = base + c;
#pragma unroll
            for (int q = 0; q < 4; ++q) {
                float t = fmaf(ax[q], v.x, fmaf(ay[q], v.y, fmaf(az[q], v.z, v.w)));
                // branchless top-3 insert (v_cmp/v_cndmask/v_med3)
                bool c0 = t < d0[q];
                bool c1 = t < d1[q];
                bool c2 = t < d2[q];
                i2[q] = c1 ? i1[q] : (c2 ? cand : i2[q]);   // uses old i1
                i1[q] = c0 ? i0[q] : (c1 ? cand : i1[q]);   // uses old i0
                i0[q] = c0 ? cand : i0[q];
                d2[q] = __builtin_amdgcn_fmed3f(d1[q], t, d2[q]);  // old d1
                d1[q] = __builtin_amdgcn_fmed3f(d0[q], t, d1[q]);  // old d0
                d0[q] = fminf(t, d0[q]);
            }
        }
        __syncthreads();   // protect LDS overwrite by next stage
    }

    // butterfly merge across the 16 splits (lex tie-break by true index)
#pragma unroll
    for (int st = 1; st <= 8; st <<= 1) {
#pragma unroll
        for (int q = 0; q < 4; ++q) {
            float e0 = __shfl_xor(d0[q], st, 64);
            float e1 = __shfl_xor(d1[q], st, 64);
            float e2 = __shfl_xor(d2[q], st, 64);
            int   j0 = __shfl_xor(i0[q], st, 64);
            int   j1 = __shfl_xor(i1[q], st, 64);
            int   j2 = __shfl_xor(i2[q], st, 64);
            ins3lex(e0, j0, d0[q], d1[q], d2[q], i0[q], i1[q], i2[q]);
            ins3lex(e1, j1, d0[q], d1[q], d2[q], i0[q], i1[q], i2[q]);
            ins3lex(e2, j2, d0[q], d1[q], d2[q], i0[q], i1[q], i2[q]);
        }
    }

    if (s == 0) {
#pragma unroll
        for (int q = 0; q < 4; ++q) {
            float r0 = 1.f / (d0[q] + pp[q]);
            float r1 = 1.f / (d1[q] + pp[q]);
            float r2 = 1.f / (d2[q] + pp[q]);
            float inv = 1.f / (r0 + r1 + r2);
            size_t o3 = ((size_t)b * N1 + p0 + q) * 3;
            idx3[o3]     = i0[q];
            idx3[o3 + 1] = i1[q];
            idx3[o3 + 2] = i2[q];
            w3[o3]     = r0 * inv;
            w3[o3 + 1] = r1 * inv;
            w3[o3 + 2] = r2 * inv;
        }
    }
}

// =====================================================================
// Fused interpolate + concat + MLP(384->256->256, BN+ReLU) + channel max
// block = 256 thr (4 waves, 2x2 over o/p), 64 points per block
// =====================================================================
__global__ __launch_bounds__(256, 2) void mlp_kernel(
    const float* __restrict__ points1, const float* __restrict__ pointsb1,
    const float4* __restrict__ p2t4,
    const int* __restrict__ idx3, const float* __restrict__ w3,
    const uint4* __restrict__ W0v, const uint4* __restrict__ W1v,
    const float* __restrict__ sst, float* __restrict__ out)
{
    // x: 64 rows x 384 fp16, 16B-chunk swizzled by (p&7); h1 overlays (64x256)
    __shared__ __align__(16) u16 sx[64 * KIN];   // 49152 B
    __shared__ float sred[2][64];
    __shared__ int   s_idx[192];
    __shared__ float s_w[192];

    int tid = threadIdx.x;
    int b   = blockIdx.y;
    int n0  = blockIdx.x * 64;

    if (tid < 192) {
        size_t gi = ((size_t)b * N1 + n0) * 3 + tid;
        s_idx[tid] = idx3[gi];
        s_w[tid]   = w3[gi];
    }
    __syncthreads();

    // ---- stage x rows 0..127 (points1) ----
    for (int i = tid; i < 2048; i += 256) {
        int p = i & 63, r4 = (i >> 6) * 4;
        size_t base = ((size_t)b * CC + r4) * N1 + n0 + p;
        float a0 = points1[base];
        float a1 = points1[base + (size_t)N1];
        float a2 = points1[base + (size_t)2 * N1];
        float a3 = points1[base + (size_t)3 * N1];
        u32 lo = f2h(a0) | ((u32)f2h(a1) << 16);
        u32 hi = f2h(a2) | ((u32)f2h(a3) << 16);
        int chunk = (r4 >> 3) ^ (p & 7);
        *(uint2*)&sx[p * KIN + chunk * 8 + (r4 & 7)] = make_uint2(lo, hi);
    }
    // ---- stage x rows 256..383 (points_b1) ----
    for (int i = tid; i < 2048; i += 256) {
        int p = i & 63, r4 = (i >> 6) * 4;
        size_t base = ((size_t)b * CC + r4) * N1 + n0 + p;
        float a0 = pointsb1[base];
        float a1 = pointsb1[base + (size_t)N1];
        float a2 = pointsb1[base + (size_t)2 * N1];
        float a3 = pointsb1[base + (size_t)3 * N1];
        int k4 = 256 + r4;
        u32 lo = f2h(a0) | ((u32)f2h(a1) << 16);
        u32 hi = f2h(a2) | ((u32)f2h(a3) << 16);
        int chunk = (k4 >> 3) ^ (p & 7);
        *(uint2*)&sx[p * KIN + chunk * 8 + (k4 & 7)] = make_uint2(lo, hi);
    }
    // ---- stage x rows 128..255: 3-NN interpolation from p2t rows ----
    for (int i = tid; i < 2048; i += 256) {
        int c4 = i & 31, p = i >> 5;
        float w0w = s_w[p * 3 + 0], w1w = s_w[p * 3 + 1], w2w = s_w[p * 3 + 2];
        float4 f0 = p2t4[((size_t)b * N2 + s_idx[p * 3 + 0]) * 32 + c4];
        float4 f1 = p2t4[((size_t)b * N2 + s_idx[p * 3 + 1]) * 32 + c4];
        float4 f2 = p2t4[((size_t)b * N2 + s_idx[p * 3 + 2]) * 32 + c4];
        float e0 = fmaf(w0w, f0.x, fmaf(w1w, f1.x, w2w * f2.x));
        float e1 = fmaf(w0w, f0.y, fmaf(w1w, f1.y, w2w * f2.y));
        float e2 = fmaf(w0w, f0.z, fmaf(w1w, f1.z, w2w * f2.z));
        float e3 = fmaf(w0w, f0.w, fmaf(w1w, f1.w, w2w * f2.w));
        int k4 = 128 + c4 * 4;
        u32 lo = f2h(e0) | ((u32)f2h(e1) << 16);
        u32 hi = f2h(e2) | ((u32)f2h(e3) << 16);
        int chunk = (k4 >> 3) ^ (p & 7);
        *(uint2*)&sx[p * KIN + chunk * 8 + (k4 & 7)] = make_uint2(lo, hi);
    }
    __syncthreads();

    int lane = tid & 63, wave = tid >> 6;
    int wo = wave >> 1, wp = wave & 1;      // o-half, p-half
    int ml = lane & 15, ql = lane >> 4;     // frag row/col, quad
    int p0  = wp * 32 + ml;                 // p for pt=0 (pt=1: +16)
    int px7 = ml & 7;                       // == p&7 for both pt

    // ---------------- GEMM1: h1 = W0 @ x ----------------
    v4f acc1[8][2];
#pragma unroll
    for (int ot = 0; ot < 8; ++ot)
        for (int pt = 0; pt < 2; ++pt)
            acc1[ot][pt] = (v4f){0.f, 0.f, 0.f, 0.f};

#pragma unroll
    for (int s = 0; s < 12; ++s) {
        int kc = s * 4 + ql;
        int pc = (kc ^ px7) * 8;
        v8h bf0 = __builtin_bit_cast(v8h, *(const uint4*)&sx[p0 * KIN + pc]);
        v8h bf1 = __builtin_bit_cast(v8h, *(const uint4*)&sx[(p0 + 16) * KIN + pc]);
#pragma unroll
        for (int ot = 0; ot < 8; ++ot) {
            int o = wo * 128 + ot * 16 + ml;
            v8h af = __builtin_bit_cast(v8h, W0v[o * 48 + kc]);
            acc1[ot][0] = __builtin_amdgcn_mfma_f32_16x16x32_f16(af, bf0, acc1[ot][0], 0, 0, 0);
            acc1[ot][1] = __builtin_amdgcn_mfma_f32_16x16x32_f16(af, bf1, acc1[ot][1], 0, 0, 0);
        }
    }
    __syncthreads();   // all x reads done before h1 overlays sx

    // epilogue 1: BN+ReLU -> fp16 h1[p][o] (row stride 256, swizzled)
    const float* s0v = sst;
    const float* t0v = sst + 256;
#pragma unroll
    for (int ot = 0; ot < 8; ++ot) {
        int o0 = wo * 128 + ot * 16 + ql * 4;
        float sc0 = s0v[o0], sc1 = s0v[o0 + 1], sc2 = s0v[o0 + 2], sc3 = s0v[o0 + 3];
        float sh0 = t0v[o0], sh1 = t0v[o0 + 1], sh2 = t0v[o0 + 2], sh3 = t0v[o0 + 3];
        int chunk = ((o0 >> 3) ^ px7);
#pragma unroll
        for (int pt = 0; pt < 2; ++pt) {
            int p = p0 + pt * 16;
            float z0 = fmaxf(fmaf(acc1[ot][pt][0], sc0, sh0), 0.f);
            float z1 = fmaxf(fmaf(acc1[ot][pt][1], sc1, sh1), 0.f);
            float z2 = fmaxf(fmaf(acc1[ot][pt][2], sc2, sh2), 0.f);
            float z3 = fmaxf(fmaf(acc1[ot][pt][3], sc3, sh3), 0.f);
            u32 lo = f2h(z0) | ((u32)f2h(z1) << 16);
            u32 hi = f2h(z2) | ((u32)f2h(z3) << 16);
            *(uint2*)&sx[p * HID + chunk * 8 + (o0 & 7)] = make_uint2(lo, hi);
        }
    }
    __syncthreads();

    // ---------------- GEMM2: h2 = W1 @ h1 ----------------
    v4f acc2[8][2];
#pragma unroll
    for (int ot = 0; ot < 8; ++ot)
        for (int pt = 0; pt < 2; ++pt)
            acc2[ot][pt] = (v4f){0.f, 0.f, 0.f, 0.f};

#pragma unroll
    for (int s = 0; s < 8; ++s) {
        int kc = s * 4 + ql;
        int pc = (kc ^ px7) * 8;
        v8h bf0 = __builtin_bit_cast(v8h, *(const uint4*)&sx[p0 * HID + pc]);
        v8h bf1 = __builtin_bit_cast(v8h, *(const uint4*)&sx[(p0 + 16) * HID + pc]);
#pragma unroll
        for (int ot = 0; ot < 8; ++ot) {
            int o = wo * 128 + ot * 16 + ml;
            v8h af = __builtin_bit_cast(v8h, W1v[o * 32 + kc]);
            acc2[ot][0] = __builtin_amdgcn_mfma_f32_16x16x32_f16(af, bf0, acc2[ot][0], 0, 0, 0);
            acc2[ot][1] = __builtin_amdgcn_mfma_f32_16x16x32_f16(af, bf1, acc2[ot][1], 0, 0, 0);
        }
    }

    // epilogue 2: BN + ReLU (via max with 0) + channel max
    const float* s1v = sst + 512;
    const float* t1v = sst + 768;
    float mx0 = 0.f, mx1 = 0.f;   // relu floor = 0
#pragma unroll
    for (int ot = 0; ot < 8; ++ot) {
        int o0 = wo * 128 + ot * 16 + ql * 4;
#pragma unroll
        for (int r = 0; r < 4; ++r) {
            float sc = s1v[o0 + r], sh = t1v[o0 + r];
            mx0 = fmaxf(mx0, fmaf(acc2[ot][0][r], sc, sh));
            mx1 = fmaxf(mx1, fmaf(acc2[ot][1][r], sc, sh));
        }
    }
    mx0 = fmaxf(mx0, __shfl_xor(mx0, 16, 64));
    mx0 = fmaxf(mx0, __shfl_xor(mx0, 32, 64));
    mx1 = fmaxf(mx1, __shfl_xor(mx1, 16, 64));
    mx1 = fmaxf(mx1, __shfl_xor(mx1, 32, 64));
    if (lane < 16) {
        sred[wo][wp * 32 + lane]      = mx0;
        sred[wo][wp * 32 + 16 + lane] = mx1;
    }
    __syncthreads();
    if (tid < 64)
        out[(size_t)b * N1 + n0 + tid] = fmaxf(sred[0][tid], sred[1][tid]);
}

// =====================================================================
extern "C" void kernel_launch(void* const* d_in, const int* in_sizes, int n_in,
                              void* d_out, int out_size, void* d_ws, size_t ws_size,
                              hipStream_t stream)
{
    const float* xyz1     = (const float*)d_in[0];
    const float* xyz2     = (const float*)d_in[1];
    const float* points2  = (const float*)d_in[2];
    const float* points1  = (const float*)d_in[3];
    const float* pointsb1 = (const float*)d_in[4];
    const float* w0   = (const float*)d_in[5];
    const float* b0   = (const float*)d_in[6];
    const float* g0   = (const float*)d_in[7];
    const float* be0  = (const float*)d_in[8];
    const float* m0   = (const float*)d_in[9];
    const float* v0   = (const float*)d_in[10];
    const float* w1   = (const float*)d_in[11];
    const float* b1   = (const float*)d_in[12];
    const float* g1   = (const float*)d_in[13];
    const float* be1  = (const float*)d_in[14];
    const float* m1   = (const float*)d_in[15];
    const float* v1   = (const float*)d_in[16];
    float* out = (float*)d_out;

    char* ws = (char*)d_ws;
    u16*    W0h   = (u16*)(ws + 0);
    u16*    W1h   = (u16*)(ws + 196608);
    float*  sst   = (float*)(ws + 327680);
    float4* xyz2q = (float4*)(ws + 331776);
    int*    idx3  = (int*)(ws + 593920);
    float*  w3    = (float*)(ws + 1380352);
    float*  p2t   = (float*)(ws + 2166784);

    prep_kernel<<<706, 256, 0, stream>>>(w0, w1, b0, g0, be0, m0, v0,
                                         b1, g1, be1, m1, v1, xyz2,
                                         W0h, W1h, sst, xyz2q);
    transpose_kernel<<<dim3(64, 4, 4), 256, 0, stream>>>(points2, p2t);
    knn_kernel<<<dim3(256, 4), 256, 0, stream>>>(xyz1, xyz2q, idx3, w3);
    mlp_kernel<<<dim3(256, 4), 256, 0, stream>>>(points1, pointsb1,
                                                 (const float4*)p2t, idx3, w3,
                                                 (const uint4*)W0h, (const uint4*)W1h,
                                                 sst, out);
}